// Round 2
// baseline (502.004 us; speedup 1.0000x reference)
//
#include <hip/hip_runtime.h>
#include <math.h>

#define MTOT 32768   // B*S = 8*4096 tokens
#define KDIM 512
#define NDIM 512

typedef __attribute__((ext_vector_type(8))) short short8;   // 8 x bf16 (4 VGPRs)
typedef __attribute__((ext_vector_type(4))) float f32x4;    // 4 x fp32
typedef __attribute__((ext_vector_type(4))) unsigned int uint4v;

__device__ __forceinline__ unsigned short f2b(float f) {
  unsigned int u = __builtin_bit_cast(unsigned int, f);
  u = (u + 0x7fffu + ((u >> 16) & 1u)) >> 16;   // RNE fp32->bf16
  return (unsigned short)u;
}
__device__ __forceinline__ float b2f(unsigned short h) {
  unsigned int u = ((unsigned int)h) << 16;
  return __builtin_bit_cast(float, u);
}

// tanh(x) = 1 - 2/(exp(2x)+1). __expf -> v_exp_f32; ~6 ops vs ~30 for tanhf.
// x->+inf: e=inf -> 1;  x->-inf: e=0 -> -1.  Error ~few fp32 ulp << bf16 rounding.
__device__ __forceinline__ float fast_tanh(float x) {
  float e = __expf(2.0f * x);
  return 1.0f - 2.0f / (e + 1.0f);
}

// async global->LDS DMA, 16B per lane. LDS dest = wave-uniform base + lane*16.
__device__ __forceinline__ void async_copy16(const unsigned short* g, unsigned short* l) {
  __builtin_amdgcn_global_load_lds(
      (const __attribute__((address_space(1))) unsigned int*)g,
      (__attribute__((address_space(3))) unsigned int*)l, 16, 0, 0);
}

// ---------------------------------------------------------------------------
// x [MTOT][512] fp32 -> bf16, 8 elems/thread
// ---------------------------------------------------------------------------
__global__ __launch_bounds__(256)
void xcast_k(const float* __restrict__ x, unsigned short* __restrict__ out) {
  const size_t i = ((size_t)blockIdx.x * 256 + threadIdx.x) * 8;
  f32x4 a = *(const f32x4*)(x + i);
  f32x4 b = *(const f32x4*)(x + i + 4);
  unsigned short t[8] __attribute__((aligned(16)));
  t[0]=f2b(a[0]); t[1]=f2b(a[1]); t[2]=f2b(a[2]); t[3]=f2b(a[3]);
  t[4]=f2b(b[0]); t[5]=f2b(b[1]); t[6]=f2b(b[2]); t[7]=f2b(b[3]);
  *(uint4v*)(out + i) = *(const uint4v*)t;
}

// ---------------------------------------------------------------------------
// Transpose all four [512][512] fp32 weights into [N][K] bf16 in one launch.
// ---------------------------------------------------------------------------
__global__ __launch_bounds__(256)
void transpose_w4(const float* __restrict__ i0, const float* __restrict__ i1,
                  const float* __restrict__ i2, const float* __restrict__ i3,
                  unsigned short* __restrict__ o0, unsigned short* __restrict__ o1,
                  unsigned short* __restrict__ o2, unsigned short* __restrict__ o3) {
  const float* in;
  unsigned short* out;
  switch (blockIdx.z) {
    case 0: in = i0; out = o0; break;
    case 1: in = i1; out = o1; break;
    case 2: in = i2; out = o2; break;
    default: in = i3; out = o3; break;
  }
  __shared__ float t[32][33];
  const int tx = threadIdx.x, ty = threadIdx.y;       // 32 x 8
  const int n0 = blockIdx.x * 32, k0 = blockIdx.y * 32;
  #pragma unroll
  for (int i = 0; i < 32; i += 8)
    t[ty + i][tx] = in[(size_t)(k0 + ty + i) * NDIM + (n0 + tx)];
  __syncthreads();
  #pragma unroll
  for (int i = 0; i < 32; i += 8)
    out[(size_t)(n0 + ty + i) * KDIM + (k0 + tx)] = f2b(t[tx][ty + i]);
}

// ---------------------------------------------------------------------------
// bf16 MFMA GEMM: C[M][512] = act(A[M][512] x W[512][512] + b)
// 128x128 tile, 256 thr (4 waves 2x2), 64x64/wave, 4x4 16x16x32 MFMA.
// BK=64 (8 K-iters), global_load_lds width=16 into XOR-swizzled [128][64]
// LDS tiles (16B chunk c of row r stored at phys chunk c^(r&7)) -> frag
// ds_read_b128 is 2-way bank aliasing (free).  Block-id swizzle co-locates
// the 4 N-chunks of each M-group on one XCD for A-tile L2 sharing.
// ACT: 0=tanh->bf16, 1=+bias->bf16, 2=relu->bf16,
//      3=final: out[m][n][4] fp32 = {c+bias, im, im, im}, im=noise*sin(alpha*n)
// ---------------------------------------------------------------------------
template<int ACT>
__global__ __launch_bounds__(256, 4)
void gemm_k(const unsigned short* __restrict__ A,    // [M][K] bf16
            const unsigned short* __restrict__ Bt,   // [N][K] bf16
            const float* __restrict__ bias,          // [N] fp32
            unsigned short* __restrict__ Cout,       // [M][N] bf16 (ACT<3)
            const float* __restrict__ noise,         // [M][N] fp32 (ACT==3)
            const float* __restrict__ alphap,        // scalar (ACT==3)
            float* __restrict__ Out4)                // [M][N][4] fp32 (ACT==3)
{
  __shared__ __align__(16) unsigned short As[128][64];
  __shared__ __align__(16) unsigned short Bs[128][64];

  const int tid  = threadIdx.x;
  const int wave = tid >> 6, lane = tid & 63;
  const int quad = lane >> 4, l16 = lane & 15;
  const int wm = (wave >> 1) * 64, wn = (wave & 1) * 64;

  // XCD co-location: ids with equal id%8 land on the same XCD (round-robin
  // dispatch heuristic — affects locality only, not correctness).
  const int id  = blockIdx.x;           // 0..1023
  const int xcd = id & 7;
  const int s   = id >> 3;
  const int bn  = (s & 3) * 128;        // 4 N-chunks, same xcd for fixed M-group
  const int bm  = ((s >> 2) * 8 + xcd) * 128;

  // DMA: wave w stages rows [w*32, w*32+32), 8 rows per call.
  // lane i -> row (i>>3), phys chunk (i&7); source = logical chunk (i&7)^(i>>3)
  // (row&7 == lane>>3 for all calls since call stride is 8 rows).
  const int r8 = lane >> 3;
  const int lc = (lane & 7) ^ r8;       // XOR-swizzled source chunk
  const unsigned short* aSrc = A  + (size_t)(bm + wave*32 + r8) * KDIM + lc*8;
  const unsigned short* bSrc = Bt + (size_t)(bn + wave*32 + r8) * KDIM + lc*8;

  f32x4 acc[4][4] = {};

  for (int k0 = 0; k0 < KDIM; k0 += 64) {
    #pragma unroll
    for (int j = 0; j < 4; j++) {
      async_copy16(aSrc + j*8*KDIM + k0, &As[wave*32 + j*8][0]);
      async_copy16(bSrc + j*8*KDIM + k0, &Bs[wave*32 + j*8][0]);
    }
    __syncthreads();   // drains vmcnt before barrier

    #pragma unroll
    for (int kc = 0; kc < 2; kc++) {
      // logical col = kc*32 + quad*8 shorts = chunk kc*4+quad; phys = ^(row&7)
      const int ca = (((kc*4 + quad) ^ (l16 & 7)) * 8);
      short8 af[4], bfr[4];
      #pragma unroll
      for (int mi = 0; mi < 4; mi++)
        af[mi] = *(const short8*)&As[wm + mi*16 + l16][ca];
      #pragma unroll
      for (int ni = 0; ni < 4; ni++)
        bfr[ni] = *(const short8*)&Bs[wn + ni*16 + l16][ca];
      __builtin_amdgcn_s_setprio(1);
      #pragma unroll
      for (int mi = 0; mi < 4; mi++)
        #pragma unroll
        for (int ni = 0; ni < 4; ni++)
          acc[mi][ni] = __builtin_amdgcn_mfma_f32_16x16x32_bf16(
              af[mi], bfr[ni], acc[mi][ni], 0, 0, 0);
      __builtin_amdgcn_s_setprio(0);
    }
    __syncthreads();
  }

  // ---- epilogue.  C/D layout: row = quad*4 + reg, col = lane&15 (m89/m91)
  float bias_v[4];
  #pragma unroll
  for (int ni = 0; ni < 4; ni++) bias_v[ni] = bias[bn + wn + ni*16 + l16];

  if (ACT == 3) {
    const float alpha = alphap[0];
    float fmod[4];
    #pragma unroll
    for (int ni = 0; ni < 4; ni++)
      fmod[ni] = sinf(alpha * (float)(bn + wn + ni*16 + l16));
    #pragma unroll
    for (int mi = 0; mi < 4; mi++) {
      #pragma unroll
      for (int ni = 0; ni < 4; ni++) {
        const int n = bn + wn + ni*16 + l16;
        #pragma unroll
        for (int r = 0; r < 4; r++) {
          const int m = bm + wm + mi*16 + quad*4 + r;
          const float c  = acc[mi][ni][r] + bias_v[ni];
          const float im = noise[(size_t)m * NDIM + n] * fmod[ni];
          f32x4 o; o[0] = c; o[1] = im; o[2] = im; o[3] = im;
          *(f32x4*)&Out4[((size_t)m * NDIM + n) * 4] = o;   // 16B coalesced
        }
      }
    }
  } else {
    #pragma unroll
    for (int mi = 0; mi < 4; mi++) {
      #pragma unroll
      for (int ni = 0; ni < 4; ni++) {
        const int n = bn + wn + ni*16 + l16;
        #pragma unroll
        for (int r = 0; r < 4; r++) {
          const int m = bm + wm + mi*16 + quad*4 + r;
          float c = acc[mi][ni][r] + bias_v[ni];
          if (ACT == 0) c = fast_tanh(c);
          if (ACT == 2) c = fmaxf(c, 0.0f);
          Cout[(size_t)m * NDIM + n] = f2b(c);
        }
      }
    }
  }
}

// ---------------------------------------------------------------------------
// Kuramoto: 10 fused steps, one wave per token, 8 phases/lane in registers.
// ---------------------------------------------------------------------------
__global__ __launch_bounds__(256)
void kuramoto_k(unsigned short* __restrict__ P,
                const float* __restrict__ omega,
                const float* __restrict__ Kp)
{
  const int lane  = threadIdx.x & 63;
  const int token = blockIdx.x * 4 + (threadIdx.x >> 6);
  const size_t base = (size_t)token * 512;
  const float Ks = Kp[0] * (1.0f / 512.0f);   // fold mean's divide into K

  float ph[8], om[8];
  #pragma unroll
  for (int i = 0; i < 8; i++) {
    ph[i] = b2f(P[base + i*64 + lane]);
    om[i] = omega[i*64 + lane];
  }
  #pragma unroll
  for (int s = 0; s < 10; s++) {
    float sum = 0.0f;
    #pragma unroll
    for (int i = 0; i < 8; i++) sum += __sinf(ph[i]);
    #pragma unroll
    for (int off = 32; off > 0; off >>= 1) sum += __shfl_xor(sum, off, 64);
    const float mf = Ks * sum;
    #pragma unroll
    for (int i = 0; i < 8; i++) ph[i] += 0.01f * (om[i] + mf * __cosf(ph[i]));
  }
  #pragma unroll
  for (int i = 0; i < 8; i++) P[base + i*64 + lane] = f2b(ph[i]);
}

// ---------------------------------------------------------------------------
extern "C" void kernel_launch(void* const* d_in, const int* in_sizes, int n_in,
                              void* d_out, int out_size, void* d_ws, size_t ws_size,
                              hipStream_t stream) {
  const float* x      = (const float*)d_in[0];
  const float* W1     = (const float*)d_in[1];
  const float* b1     = (const float*)d_in[2];
  const float* W2     = (const float*)d_in[3];
  const float* b2     = (const float*)d_in[4];
  const float* omega  = (const float*)d_in[5];
  const float* Kp     = (const float*)d_in[6];
  const float* alphap = (const float*)d_in[7];
  const float* F1     = (const float*)d_in[8];
  const float* c1     = (const float*)d_in[9];
  const float* F2     = (const float*)d_in[10];
  const float* c2     = (const float*)d_in[11];
  const float* noise  = (const float*)d_in[12];
  float* out = (float*)d_out;

  // workspace: 4 x 512KB bf16 transposed weights + 3 x 32MB bf16 activations
  char* ws = (char*)d_ws;
  unsigned short* wt1  = (unsigned short*)(ws + 0 * (512 * 1024));
  unsigned short* wt2  = (unsigned short*)(ws + 1 * (512 * 1024));
  unsigned short* wt3  = (unsigned short*)(ws + 2 * (512 * 1024));
  unsigned short* wt4  = (unsigned short*)(ws + 3 * (512 * 1024));
  unsigned short* xb   = (unsigned short*)(ws + 4 * (512 * 1024));
  unsigned short* bufA = xb   + (size_t)MTOT * 512;
  unsigned short* bufB = bufA + (size_t)MTOT * 512;

  dim3 tb(32, 8), tg(16, 16, 4);
  transpose_w4<<<tg, tb, 0, stream>>>(W1, W2, F1, F2, wt1, wt2, wt3, wt4);
  xcast_k<<<(MTOT * KDIM) / (256 * 8), 256, 0, stream>>>(x, xb);

  const int gg = 1024;   // 1D grid, swizzle-decoded in-kernel
  gemm_k<0><<<gg, 256, 0, stream>>>(xb,   wt1, b1, bufA, nullptr, nullptr, nullptr);
  gemm_k<1><<<gg, 256, 0, stream>>>(bufA, wt2, b2, bufB, nullptr, nullptr, nullptr);
  kuramoto_k<<<MTOT / 4, 256, 0, stream>>>(bufB, omega, Kp);
  gemm_k<2><<<gg, 256, 0, stream>>>(bufB, wt3, c1, bufA, nullptr, nullptr, nullptr);
  gemm_k<3><<<gg, 256, 0, stream>>>(bufA, wt4, c2, nullptr, noise, alphap, out);
}

// Round 3
// 498.572 us; speedup vs baseline: 1.0069x; 1.0069x over previous
//
#include <hip/hip_runtime.h>
#include <math.h>

#define MTOT 32768   // B*S = 8*4096 tokens
#define KDIM 512
#define NDIM 512

typedef __attribute__((ext_vector_type(8))) short short8;   // 8 x bf16 (4 VGPRs)
typedef __attribute__((ext_vector_type(4))) float f32x4;    // 4 x fp32
typedef __attribute__((ext_vector_type(4))) unsigned int uint4v;

__device__ __forceinline__ unsigned short f2b(float f) {
  unsigned int u = __builtin_bit_cast(unsigned int, f);
  u = (u + 0x7fffu + ((u >> 16) & 1u)) >> 16;   // RNE fp32->bf16
  return (unsigned short)u;
}
__device__ __forceinline__ float b2f(unsigned short h) {
  unsigned int u = ((unsigned int)h) << 16;
  return __builtin_bit_cast(float, u);
}

// tanh(x) = 1 - 2/(exp(2x)+1). __expf -> v_exp_f32; ~6 ops vs ~30 for tanhf.
__device__ __forceinline__ float fast_tanh(float x) {
  float e = __expf(2.0f * x);
  return 1.0f - 2.0f / (e + 1.0f);
}

// async global->LDS DMA, 16B per lane. LDS dest = wave-uniform base + lane*16.
__device__ __forceinline__ void async_copy16(const unsigned short* g, unsigned short* l) {
  __builtin_amdgcn_global_load_lds(
      (const __attribute__((address_space(1))) unsigned int*)g,
      (__attribute__((address_space(3))) unsigned int*)l, 16, 0, 0);
}

// ---------------------------------------------------------------------------
// x [MTOT][512] fp32 -> bf16, 8 elems/thread
// ---------------------------------------------------------------------------
__global__ __launch_bounds__(256)
void xcast_k(const float* __restrict__ x, unsigned short* __restrict__ out) {
  const size_t i = ((size_t)blockIdx.x * 256 + threadIdx.x) * 8;
  f32x4 a = *(const f32x4*)(x + i);
  f32x4 b = *(const f32x4*)(x + i + 4);
  unsigned short t[8] __attribute__((aligned(16)));
  t[0]=f2b(a[0]); t[1]=f2b(a[1]); t[2]=f2b(a[2]); t[3]=f2b(a[3]);
  t[4]=f2b(b[0]); t[5]=f2b(b[1]); t[6]=f2b(b[2]); t[7]=f2b(b[3]);
  *(uint4v*)(out + i) = *(const uint4v*)t;
}

// ---------------------------------------------------------------------------
// Transpose all four [512][512] fp32 weights into [N][K] bf16 in one launch.
// ---------------------------------------------------------------------------
__global__ __launch_bounds__(256)
void transpose_w4(const float* __restrict__ i0, const float* __restrict__ i1,
                  const float* __restrict__ i2, const float* __restrict__ i3,
                  unsigned short* __restrict__ o0, unsigned short* __restrict__ o1,
                  unsigned short* __restrict__ o2, unsigned short* __restrict__ o3) {
  const float* in;
  unsigned short* out;
  switch (blockIdx.z) {
    case 0: in = i0; out = o0; break;
    case 1: in = i1; out = o1; break;
    case 2: in = i2; out = o2; break;
    default: in = i3; out = o3; break;
  }
  __shared__ float t[32][33];
  const int tx = threadIdx.x, ty = threadIdx.y;       // 32 x 8
  const int n0 = blockIdx.x * 32, k0 = blockIdx.y * 32;
  #pragma unroll
  for (int i = 0; i < 32; i += 8)
    t[ty + i][tx] = in[(size_t)(k0 + ty + i) * NDIM + (n0 + tx)];
  __syncthreads();
  #pragma unroll
  for (int i = 0; i < 32; i += 8)
    out[(size_t)(n0 + ty + i) * KDIM + (k0 + tx)] = f2b(t[tx][ty + i]);
}

// ---------------------------------------------------------------------------
// bf16 MFMA GEMM: C[M][512] = act(A[M][512] x W[512][512] + b)
// 128x128 tile, 256 thr (4 waves 2x2), 64x64/wave, 4x4 16x16x32 MFMA.
// BK=64 (8 K-iters), global_load_lds width=16 into XOR-swizzled [128][64]
// LDS tiles -> frag ds_read_b128 is 2-way bank aliasing (free).
// launch_bounds (256,2): 2 waves/EU -> 256-reg cap.  (256,4) capped the
// unified VGPR+AGPR file at 128/lane but the kernel needs ~230 (acc 64 +
// frags 32 + addr/epilogue) -> spill risk; m97-lineage allocates 164V+64A.
// ACT: 0=tanh->bf16, 1=+bias->bf16, 2=relu->bf16,
//      3=final: out[m][n][4] fp32 = {c+bias, im, im, im}, im=noise*sin(alpha*n)
// ---------------------------------------------------------------------------
template<int ACT>
__global__ __launch_bounds__(256, 2)
void gemm_k(const unsigned short* __restrict__ A,    // [M][K] bf16
            const unsigned short* __restrict__ Bt,   // [N][K] bf16
            const float* __restrict__ bias,          // [N] fp32
            unsigned short* __restrict__ Cout,       // [M][N] bf16 (ACT<3)
            const float* __restrict__ noise,         // [M][N] fp32 (ACT==3)
            const float* __restrict__ alphap,        // scalar (ACT==3)
            float* __restrict__ Out4)                // [M][N][4] fp32 (ACT==3)
{
  __shared__ __align__(16) unsigned short As[128][64];
  __shared__ __align__(16) unsigned short Bs[128][64];

  const int tid  = threadIdx.x;
  const int wave = tid >> 6, lane = tid & 63;
  const int quad = lane >> 4, l16 = lane & 15;
  const int wm = (wave >> 1) * 64, wn = (wave & 1) * 64;

  // XCD co-location: ids with equal id%8 land on the same XCD (round-robin
  // dispatch heuristic — affects locality only, not correctness).
  const int id  = blockIdx.x;           // 0..1023
  const int xcd = id & 7;
  const int s   = id >> 3;
  const int bn  = (s & 3) * 128;        // 4 N-chunks, same xcd for fixed M-group
  const int bm  = ((s >> 2) * 8 + xcd) * 128;

  // DMA: wave w stages rows [w*32, w*32+32), 8 rows per call.
  // lane i -> row (i>>3), phys chunk (i&7); source = logical chunk (i&7)^(i>>3)
  const int r8 = lane >> 3;
  const int lc = (lane & 7) ^ r8;       // XOR-swizzled source chunk
  const unsigned short* aSrc = A  + (size_t)(bm + wave*32 + r8) * KDIM + lc*8;
  const unsigned short* bSrc = Bt + (size_t)(bn + wave*32 + r8) * KDIM + lc*8;

  f32x4 acc[4][4] = {};

  for (int k0 = 0; k0 < KDIM; k0 += 64) {
    #pragma unroll
    for (int j = 0; j < 4; j++) {
      async_copy16(aSrc + j*8*KDIM + k0, &As[wave*32 + j*8][0]);
      async_copy16(bSrc + j*8*KDIM + k0, &Bs[wave*32 + j*8][0]);
    }
    __syncthreads();   // drains vmcnt before barrier

    #pragma unroll
    for (int kc = 0; kc < 2; kc++) {
      // logical col = kc*32 + quad*8 shorts = chunk kc*4+quad; phys = ^(row&7)
      const int ca = (((kc*4 + quad) ^ (l16 & 7)) * 8);
      short8 af[4], bfr[4];
      #pragma unroll
      for (int mi = 0; mi < 4; mi++)
        af[mi] = *(const short8*)&As[wm + mi*16 + l16][ca];
      #pragma unroll
      for (int ni = 0; ni < 4; ni++)
        bfr[ni] = *(const short8*)&Bs[wn + ni*16 + l16][ca];
      __builtin_amdgcn_s_setprio(1);
      #pragma unroll
      for (int mi = 0; mi < 4; mi++)
        #pragma unroll
        for (int ni = 0; ni < 4; ni++)
          acc[mi][ni] = __builtin_amdgcn_mfma_f32_16x16x32_bf16(
              af[mi], bfr[ni], acc[mi][ni], 0, 0, 0);
      __builtin_amdgcn_s_setprio(0);
    }
    __syncthreads();
  }

  // ---- epilogue.  C/D layout: row = quad*4 + reg, col = lane&15 (m89/m91)
  float bias_v[4];
  #pragma unroll
  for (int ni = 0; ni < 4; ni++) bias_v[ni] = bias[bn + wn + ni*16 + l16];

  if (ACT == 3) {
    const float alpha = alphap[0];
    float fmod[4];
    #pragma unroll
    for (int ni = 0; ni < 4; ni++)
      fmod[ni] = sinf(alpha * (float)(bn + wn + ni*16 + l16));
    #pragma unroll
    for (int mi = 0; mi < 4; mi++) {
      #pragma unroll
      for (int ni = 0; ni < 4; ni++) {
        const int n = bn + wn + ni*16 + l16;
        #pragma unroll
        for (int r = 0; r < 4; r++) {
          const int m = bm + wm + mi*16 + quad*4 + r;
          const float c  = acc[mi][ni][r] + bias_v[ni];
          const float im = noise[(size_t)m * NDIM + n] * fmod[ni];
          f32x4 o; o[0] = c; o[1] = im; o[2] = im; o[3] = im;
          *(f32x4*)&Out4[((size_t)m * NDIM + n) * 4] = o;   // 16B coalesced
        }
      }
    }
  } else {
    #pragma unroll
    for (int mi = 0; mi < 4; mi++) {
      #pragma unroll
      for (int ni = 0; ni < 4; ni++) {
        const int n = bn + wn + ni*16 + l16;
        #pragma unroll
        for (int r = 0; r < 4; r++) {
          const int m = bm + wm + mi*16 + quad*4 + r;
          float c = acc[mi][ni][r] + bias_v[ni];
          if (ACT == 0) c = fast_tanh(c);
          if (ACT == 2) c = fmaxf(c, 0.0f);
          Cout[(size_t)m * NDIM + n] = f2b(c);
        }
      }
    }
  }
}

// ---------------------------------------------------------------------------
// Kuramoto: 10 fused steps, one wave per token, 8 phases/lane in registers.
// ---------------------------------------------------------------------------
__global__ __launch_bounds__(256)
void kuramoto_k(unsigned short* __restrict__ P,
                const float* __restrict__ omega,
                const float* __restrict__ Kp)
{
  const int lane  = threadIdx.x & 63;
  const int token = blockIdx.x * 4 + (threadIdx.x >> 6);
  const size_t base = (size_t)token * 512;
  const float Ks = Kp[0] * (1.0f / 512.0f);   // fold mean's divide into K

  float ph[8], om[8];
  #pragma unroll
  for (int i = 0; i < 8; i++) {
    ph[i] = b2f(P[base + i*64 + lane]);
    om[i] = omega[i*64 + lane];
  }
  #pragma unroll
  for (int s = 0; s < 10; s++) {
    float sum = 0.0f;
    #pragma unroll
    for (int i = 0; i < 8; i++) sum += __sinf(ph[i]);
    #pragma unroll
    for (int off = 32; off > 0; off >>= 1) sum += __shfl_xor(sum, off, 64);
    const float mf = Ks * sum;
    #pragma unroll
    for (int i = 0; i < 8; i++) ph[i] += 0.01f * (om[i] + mf * __cosf(ph[i]));
  }
  #pragma unroll
  for (int i = 0; i < 8; i++) P[base + i*64 + lane] = f2b(ph[i]);
}

// ---------------------------------------------------------------------------
extern "C" void kernel_launch(void* const* d_in, const int* in_sizes, int n_in,
                              void* d_out, int out_size, void* d_ws, size_t ws_size,
                              hipStream_t stream) {
  const float* x      = (const float*)d_in[0];
  const float* W1     = (const float*)d_in[1];
  const float* b1     = (const float*)d_in[2];
  const float* W2     = (const float*)d_in[3];
  const float* b2     = (const float*)d_in[4];
  const float* omega  = (const float*)d_in[5];
  const float* Kp     = (const float*)d_in[6];
  const float* alphap = (const float*)d_in[7];
  const float* F1     = (const float*)d_in[8];
  const float* c1     = (const float*)d_in[9];
  const float* F2     = (const float*)d_in[10];
  const float* c2     = (const float*)d_in[11];
  const float* noise  = (const float*)d_in[12];
  float* out = (float*)d_out;

  // workspace: 4 x 512KB bf16 transposed weights + 3 x 32MB bf16 activations
  char* ws = (char*)d_ws;
  unsigned short* wt1  = (unsigned short*)(ws + 0 * (512 * 1024));
  unsigned short* wt2  = (unsigned short*)(ws + 1 * (512 * 1024));
  unsigned short* wt3  = (unsigned short*)(ws + 2 * (512 * 1024));
  unsigned short* wt4  = (unsigned short*)(ws + 3 * (512 * 1024));
  unsigned short* xb   = (unsigned short*)(ws + 4 * (512 * 1024));
  unsigned short* bufA = xb   + (size_t)MTOT * 512;
  unsigned short* bufB = bufA + (size_t)MTOT * 512;

  dim3 tb(32, 8), tg(16, 16, 4);
  transpose_w4<<<tg, tb, 0, stream>>>(W1, W2, F1, F2, wt1, wt2, wt3, wt4);
  xcast_k<<<(MTOT * KDIM) / (256 * 8), 256, 0, stream>>>(x, xb);

  const int gg = 1024;   // 1D grid, swizzle-decoded in-kernel
  gemm_k<0><<<gg, 256, 0, stream>>>(xb,   wt1, b1, bufA, nullptr, nullptr, nullptr);
  gemm_k<1><<<gg, 256, 0, stream>>>(bufA, wt2, b2, bufB, nullptr, nullptr, nullptr);
  kuramoto_k<<<MTOT / 4, 256, 0, stream>>>(bufB, omega, Kp);
  gemm_k<2><<<gg, 256, 0, stream>>>(bufB, wt3, c1, bufA, nullptr, nullptr, nullptr);
  gemm_k<3><<<gg, 256, 0, stream>>>(bufA, wt4, c2, nullptr, noise, alphap, out);
}